// Round 2
// baseline (740.921 us; speedup 1.0000x reference)
//
#include <hip/hip_runtime.h>
#include <stdint.h>

#define N_TOK 4096
#define H_Q   32
#define H_KV  8
#define DH    128
#define SEQ   2048
#define BATCH (N_TOK / SEQ)
#define GRP   (H_Q / H_KV)

#define KP 136   // K_lds row pitch (bf16 elems): 272B rows -> b128 reads hit 8-words/bank min
#define VP 40    // V_lds (transposed) row pitch: 80B rows
#define PP 40    // P_lds row pitch

typedef __attribute__((ext_vector_type(8))) short bf16x8;
typedef __attribute__((ext_vector_type(4))) float f32x4;
typedef __attribute__((ext_vector_type(4))) int   i32x4;

__device__ __forceinline__ uint16_t f2bf(float x) {
  uint32_t u = __float_as_uint(x);
  u += 0x7FFFu + ((u >> 16) & 1u);   // RNE
  return (uint16_t)(u >> 16);
}
__device__ __forceinline__ uint32_t pk2(float a, float b) {
  return (uint32_t)f2bf(a) | ((uint32_t)f2bf(b) << 16);
}

// 4 waves/block, wave w owns q rows [q0+16w, q0+16w+16); KV tiles of 32.
// MFMA 16x16x32 bf16. A-frag: lane holds A[l&15][(l>>4)*8+i]; B-frag:
// B[(l>>4)*8+i][l&15]; C/D: row=(l>>4)*4+i, col=l&15 (m89-verified).
__global__ __launch_bounds__(256) void attn_fwd(
    const float* __restrict__ q, const float* __restrict__ k,
    const float* __restrict__ v, float* __restrict__ out)
{
  const int qt  = blockIdx.x;
  const int h   = blockIdx.y;
  const int b   = blockIdx.z;
  const int hkv = h / GRP;
  const int q0  = qt * 64;
  const int tid = threadIdx.x;
  const int wid = tid >> 6;
  const int lane = tid & 63;
  const int lg = lane >> 4;
  const int lr = lane & 15;

  __shared__ uint16_t K_lds[32 * KP];       // [kv][d] bf16
  __shared__ uint16_t V_lds[128 * VP];      // [d][kv] bf16 (transposed)
  __shared__ uint16_t P_lds[4][16 * PP];    // per-wave P staging

  // ---- load + pre-scale Q fragments (A-frag layout) ----
  bf16x8 qf[4];
  {
    const int qrow = q0 + wid * 16 + lr;
    const float* qp = q + ((size_t)(b * SEQ + qrow) * H_Q + h) * DH + lg * 8;
    const float sc = 0.08838834764831845f;  // 1/sqrt(128)
#pragma unroll
    for (int dblk = 0; dblk < 4; ++dblk) {
      f32x4 f0 = *(const f32x4*)(qp + dblk * 32);
      f32x4 f1 = *(const f32x4*)(qp + dblk * 32 + 4);
      i32x4 w;
      w[0] = pk2(f0[0] * sc, f0[1] * sc);
      w[1] = pk2(f0[2] * sc, f0[3] * sc);
      w[2] = pk2(f1[0] * sc, f1[1] * sc);
      w[3] = pk2(f1[2] * sc, f1[3] * sc);
      qf[dblk] = *(bf16x8*)&w;
    }
  }

  f32x4 o[8];
#pragma unroll
  for (int i = 0; i < 8; ++i) o[i] = (f32x4){0.f, 0.f, 0.f, 0.f};
  float m_i[4] = {-1e30f, -1e30f, -1e30f, -1e30f};
  float l_i[4] = {0.f, 0.f, 0.f, 0.f};

  const int nt = 2 * qt + 2;                 // causal: kv tiles up to q0+63
  const int wave_qmax = q0 + wid * 16 + 15;

  for (int t = 0; t < nt; ++t) {
    const int kv0 = t * 32;
    __syncthreads();  // protect LDS from previous iteration's readers

    // ---- stage K tile [32][128] f32 -> bf16 LDS ----
    {
      const int row = tid >> 3;
      const int c0 = (tid & 7) * 16;
      const float* kp = k + ((size_t)(b * SEQ + kv0 + row) * H_KV + hkv) * DH + c0;
      f32x4 f0 = *(const f32x4*)(kp + 0);
      f32x4 f1 = *(const f32x4*)(kp + 4);
      f32x4 f2 = *(const f32x4*)(kp + 8);
      f32x4 f3 = *(const f32x4*)(kp + 12);
      i32x4 w0, w1;
      w0[0] = pk2(f0[0], f0[1]); w0[1] = pk2(f0[2], f0[3]);
      w0[2] = pk2(f1[0], f1[1]); w0[3] = pk2(f1[2], f1[3]);
      w1[0] = pk2(f2[0], f2[1]); w1[1] = pk2(f2[2], f2[3]);
      w1[2] = pk2(f3[0], f3[1]); w1[3] = pk2(f3[2], f3[3]);
      *(i32x4*)&K_lds[row * KP + c0]     = w0;
      *(i32x4*)&K_lds[row * KP + c0 + 8] = w1;
    }
    // ---- stage V tile transposed [d][kv] ----
    {
      const int rblk = tid >> 5;          // 0..7 -> kv rows rblk*4..+3
      const int c0 = (tid & 31) * 4;      // d cols
      const float* vp = v + ((size_t)(b * SEQ + kv0 + rblk * 4) * H_KV + hkv) * DH + c0;
      const size_t vstep = (size_t)H_KV * DH;
      f32x4 r0 = *(const f32x4*)(vp);
      f32x4 r1 = *(const f32x4*)(vp + vstep);
      f32x4 r2 = *(const f32x4*)(vp + 2 * vstep);
      f32x4 r3 = *(const f32x4*)(vp + 3 * vstep);
#pragma unroll
      for (int j = 0; j < 4; ++j) {
        uint2 w;
        w.x = pk2(r0[j], r1[j]);
        w.y = pk2(r2[j], r3[j]);
        *(uint2*)&V_lds[(c0 + j) * VP + rblk * 4] = w;
      }
    }
    __syncthreads();

    if (kv0 > wave_qmax) continue;  // this wave fully masked for this tile

    // ---- S = Q K^T (two 16-col tiles over 32 kv) ----
    f32x4 s0 = (f32x4){0.f, 0.f, 0.f, 0.f};
    f32x4 s1 = (f32x4){0.f, 0.f, 0.f, 0.f};
#pragma unroll
    for (int dblk = 0; dblk < 4; ++dblk) {
      bf16x8 kb0 = *(const bf16x8*)&K_lds[lr * KP + dblk * 32 + lg * 8];
      bf16x8 kb1 = *(const bf16x8*)&K_lds[(16 + lr) * KP + dblk * 32 + lg * 8];
      s0 = __builtin_amdgcn_mfma_f32_16x16x32_bf16(qf[dblk], kb0, s0, 0, 0, 0);
      s1 = __builtin_amdgcn_mfma_f32_16x16x32_bf16(qf[dblk], kb1, s1, 0, 0, 0);
    }

    // ---- online softmax; rows r=lg*4+i live across the 16 lanes of group lg ----
    const int qbase = q0 + wid * 16 + lg * 4;
#pragma unroll
    for (int i = 0; i < 4; ++i) {
      float sv0 = s0[i], sv1 = s1[i];
      if (kv0 + lr      > qbase + i) sv0 = -1e30f;
      if (kv0 + 16 + lr > qbase + i) sv1 = -1e30f;
      float mx = fmaxf(sv0, sv1);
      mx = fmaxf(mx, __shfl_xor(mx, 1));
      mx = fmaxf(mx, __shfl_xor(mx, 2));
      mx = fmaxf(mx, __shfl_xor(mx, 4));
      mx = fmaxf(mx, __shfl_xor(mx, 8));
      const float mnew = fmaxf(m_i[i], mx);
      const float L2E = 1.4426950408889634f;
      const float r  = exp2f((m_i[i] - mnew) * L2E);
      const float p0 = exp2f((sv0 - mnew) * L2E);
      const float p1 = exp2f((sv1 - mnew) * L2E);
      float sum = p0 + p1;
      sum += __shfl_xor(sum, 1);
      sum += __shfl_xor(sum, 2);
      sum += __shfl_xor(sum, 4);
      sum += __shfl_xor(sum, 8);
      l_i[i] = l_i[i] * r + sum;
      m_i[i] = mnew;
#pragma unroll
      for (int dt = 0; dt < 8; ++dt) o[dt][i] *= r;
      // stage P (C-layout -> LDS) for A-frag reload
      P_lds[wid][(lg * 4 + i) * PP + lr]      = f2bf(p0);
      P_lds[wid][(lg * 4 + i) * PP + 16 + lr] = f2bf(p1);
    }

    // ---- O += P V ----
    bf16x8 pf = *(const bf16x8*)&P_lds[wid][lr * PP + lg * 8];
#pragma unroll
    for (int dt = 0; dt < 8; ++dt) {
      bf16x8 vb = *(const bf16x8*)&V_lds[(dt * 16 + lr) * VP + lg * 8];
      o[dt] = __builtin_amdgcn_mfma_f32_16x16x32_bf16(pf, vb, o[dt], 0, 0, 0);
    }
  }

  // ---- epilogue: out = O / l ----
#pragma unroll
  for (int i = 0; i < 4; ++i) {
    const float inv = 1.0f / l_i[i];
    const int qrow = q0 + wid * 16 + lg * 4 + i;
    float* op = out + ((size_t)(b * SEQ + qrow) * H_Q + h) * DH + lr;
#pragma unroll
    for (int dt = 0; dt < 8; ++dt) op[dt * 16] = o[dt][i] * inv;
  }
}

// ---- KV cache: copy base cache, then scatter new k/v rows by slot ----
__global__ __launch_bounds__(256) void copy_caches(
    const f32x4* __restrict__ kc_in, const f32x4* __restrict__ vc_in,
    f32x4* __restrict__ kc_out, f32x4* __restrict__ vc_out)
{
  const size_t i = (size_t)blockIdx.x * 256 + threadIdx.x;
  kc_out[i] = kc_in[i];
  vc_out[i] = vc_in[i];
}

__global__ __launch_bounds__(256) void scatter_kv(
    const f32x4* __restrict__ kin, const f32x4* __restrict__ vin,
    const int* __restrict__ slot, f32x4* __restrict__ kc_out,
    f32x4* __restrict__ vc_out)
{
  const int row = blockIdx.x;
  const int s = slot[row];
  if (s < 0) return;
  const int t = threadIdx.x;  // 256 threads x float4 = 1024 floats/row
  kc_out[(size_t)s * 256 + t] = kin[(size_t)row * 256 + t];
  vc_out[(size_t)s * 256 + t] = vin[(size_t)row * 256 + t];
}

extern "C" void kernel_launch(void* const* d_in, const int* in_sizes, int n_in,
                              void* d_out, int out_size, void* d_ws, size_t ws_size,
                              hipStream_t stream) {
  const float* q  = (const float*)d_in[0];
  const float* k  = (const float*)d_in[1];
  const float* v  = (const float*)d_in[2];
  const float* kc = (const float*)d_in[3];
  const float* vc = (const float*)d_in[4];
  const int* slot = (const int*)d_in[5];

  float* out    = (float*)d_out;
  float* kc_out = out + (size_t)N_TOK * H_Q * DH;
  float* vc_out = kc_out + (size_t)N_TOK * H_KV * DH;

  copy_caches<<<dim3((N_TOK * H_KV * DH / 4) / 256), 256, 0, stream>>>(
      (const f32x4*)kc, (const f32x4*)vc, (f32x4*)kc_out, (f32x4*)vc_out);
  scatter_kv<<<dim3(N_TOK), 256, 0, stream>>>(
      (const f32x4*)k, (const f32x4*)v, slot, (f32x4*)kc_out, (f32x4*)vc_out);
  attn_fwd<<<dim3(SEQ / 64, H_Q, BATCH), 256, 0, stream>>>(q, k, v, out);
}